// Round 20
// baseline (355.318 us; speedup 1.0000x reference)
//
#include <hip/hip_runtime.h>
#include <hip/hip_fp8.h>

#define NN 10000      // nodes
#define NE 80000      // edges
#define NG 32         // graphs
#define NZ 10         // elements
#define NC 128        // channels
#define RMAXF 5.0f

typedef _Float16 f16;
typedef _Float16 half8 __attribute__((ext_vector_type(8)));
typedef float f32x4 __attribute__((ext_vector_type(4)));

__device__ __forceinline__ float silu_f(float x) {
    return x / (1.0f + __expf(-x));
}

__device__ __forceinline__ int clampi(int v, int lo, int hi) {
    return v < lo ? lo : (v > hi ? hi : v);
}

__device__ __forceinline__ uint4 pack8f(float4 a, float4 b) {
    union { f16 h[8]; uint4 u; } P;
    P.h[0] = (f16)a.x; P.h[1] = (f16)a.y; P.h[2] = (f16)a.z; P.h[3] = (f16)a.w;
    P.h[4] = (f16)b.x; P.h[5] = (f16)b.y; P.h[6] = (f16)b.z; P.h[7] = (f16)b.w;
    return P.u;
}

// 8 x f16 -> 8 x fp8(e4m3) bytes
__device__ __forceinline__ uint2 cvt8_fp8(uint4 v) {
    union { uint4 u; f16 h[8]; } I; I.u = v;
    union { unsigned char b[8]; uint2 u2; } O;
#pragma unroll
    for (int j = 0; j < 8; j++) {
        __hip_fp8_e4m3 t((float)I.h[j]);
        O.b[j] = t.__x;
    }
    return O.u2;
}

__device__ __forceinline__ float fp8_to_f(unsigned char b) {
    __hip_fp8_e4m3 t; t.__x = b;
    return (float)t;
}

// ---------------- zero scratch / output ----------------
__global__ void zero_stuff(int* counts, int* cursor, float* out) {
    int i = blockIdx.x * blockDim.x + threadIdx.x;
    if (i < NN) { counts[i] = 0; cursor[i] = 0; }
    if (i < NG) out[i] = 0.0f;
}

// ---------------- weight prep: f16 transposed tables ----------------
__global__ void prep_weights(const float* __restrict__ Wmix, const float* __restrict__ Wprod,
                             const float* __restrict__ Wsc,
                             const float* __restrict__ rw2, const float* __restrict__ rw3,
                             const float* __restrict__ rw4,
                             f16* __restrict__ WmixT, f16* __restrict__ WprodT, f16* __restrict__ WscT,
                             f16* __restrict__ w2T, f16* __restrict__ w3T, f16* __restrict__ w4T) {
    int i = blockIdx.x * blockDim.x + threadIdx.x;
    if (i < 2 * 4 * 128 * 128) {           // WmixT[g][d][cc] = Wmix[g][cc][d]
        int cc = i & 127, d = (i >> 7) & 127, g = i >> 14;
        WmixT[i] = (f16)Wmix[((size_t)g * 128 + cc) * 128 + d];
    }
    if (i < 2 * 128 * 128) {               // WprodT[ly][d][dd] = Wprod[ly][dd][d]
        int cc = i & 127, d = (i >> 7) & 127, g = i >> 14;
        WprodT[i] = (f16)Wprod[((size_t)g * 128 + cc) * 128 + d];
        WscT[i]   = (f16)Wsc[((size_t)g * 128 + cc) * 128 + d];
    }
    if (i < 2 * 512 * 64) {                // w4T[ly][j][k] = rw4[ly][k][j]
        int k = i & 63, j = (i >> 6) & 511, ly = i >> 15;
        w4T[i] = (f16)rw4[((size_t)ly * 64 + k) * 512 + j];
    }
    if (i < 2 * 64 * 64) {                 // w2T/w3T[ly][j][k] = rw[ly][k][j]
        int k = i & 63, j = (i >> 6) & 63, ly = i >> 12;
        w2T[i] = (f16)rw2[((size_t)ly * 64 + k) * 64 + j];
        w3T[i] = (f16)rw3[((size_t)ly * 64 + k) * 64 + j];
    }
}

// ---------------- node init: h0, node_e0, wU ----------------
__global__ void node_init(const float* __restrict__ attrs, const float* __restrict__ W_embed,
                          const float* __restrict__ ae, const float* __restrict__ U,
                          float* __restrict__ h, float* __restrict__ node_e0, float* __restrict__ wU) {
    int gid = blockIdx.x * blockDim.x + threadIdx.x;
    if (gid >= NN * NC) return;
    int n = gid >> 7, c = gid & 127;
    float a[NZ];
#pragma unroll
    for (int z = 0; z < NZ; z++) a[z] = attrs[n * NZ + z];
    float acc = 0.f;
#pragma unroll
    for (int z = 0; z < NZ; z++) acc += a[z] * W_embed[z * NC + c];
    h[(size_t)n * NC + c] = acc;
    if (c == 0) {
        float e = 0.f;
#pragma unroll
        for (int z = 0; z < NZ; z++) e += a[z] * ae[z];
        node_e0[n] = e;
    }
    if (c < 8) {
        int i = c >> 2, l = c & 3;
        float s = 0.f;
#pragma unroll
        for (int z = 0; z < NZ; z++) s += a[z] * U[i * NZ * 4 + z * 4 + l];
        wU[(size_t)i * NN * 4 + n * 4 + l] = s;
    }
}

// ---------------- edge geometry (PERMUTED): slot i <- edge elist[i] ----------------
__global__ void edge_geom(const float* __restrict__ vec, const int* __restrict__ elist,
                          float* __restrict__ Y2, float* __restrict__ ef2) {
    int i = blockIdx.x * blockDim.x + threadIdx.x;
    if (i >= NE) return;
    int e = clampi(elist[i], 0, NE - 1);
    float vx = vec[e * 3 + 0], vy = vec[e * 3 + 1], vz = vec[e * 3 + 2];
    float r = sqrtf(vx * vx + vy * vy + vz * vz);
    float inv = 1.0f / r;
    float x = vx * inv, y = vy * inv, z = vz * inv;
    const float s3 = 1.7320508075688772f;
    const float s5 = 2.23606797749979f;
    const float s15 = 3.872983346207417f;
    const float c9 = 2.091650066335189f;
    const float c10 = 10.246950765959598f;
    const float c11 = 1.6201851746019651f;
    const float c12 = 1.3228756555322954f;
    const float c14 = 5.123475382979799f;
    float o[16];
    o[0] = 1.0f;
    o[1] = s3 * x; o[2] = s3 * y; o[3] = s3 * z;
    o[4] = s15 * x * y; o[5] = s15 * y * z; o[6] = 0.5f * s5 * (3.f * z * z - 1.f);
    o[7] = s15 * x * z; o[8] = 0.5f * s15 * (x * x - y * y);
    o[9] = c9 * (3.f * x * x * y - y * y * y);
    o[10] = c10 * x * y * z;
    o[11] = c11 * y * (5.f * z * z - 1.f);
    o[12] = c12 * (5.f * z * z * z - 3.f * z);
    o[13] = c11 * x * (5.f * z * z - 1.f);
    o[14] = c14 * z * (x * x - y * y);
    o[15] = c9 * (x * x * x - 3.f * x * y * y);
#pragma unroll
    for (int m = 0; m < 16; m++) Y2[(size_t)i * 16 + m] = o[m];
    float xc = r / RMAXF;
    float cut = 0.0f;
    if (xc < 1.0f) {
        float x5 = xc * xc * xc * xc * xc;
        cut = 1.0f - 21.0f * x5 + 35.0f * x5 * xc - 15.0f * x5 * xc * xc;
    }
    float pref = sqrtf(2.0f / RMAXF) * inv * cut;
#pragma unroll
    for (int b = 0; b < 8; b++) {
        float arg = (float)(b + 1) * 3.14159265358979323846f * r / RMAXF;
        ef2[(size_t)i * 8 + b] = pref * sinf(arg);
    }
}

// ---------------- CSR build ----------------
__global__ void hist_recv(const int* __restrict__ recv, int* __restrict__ counts) {
    int e = blockIdx.x * blockDim.x + threadIdx.x;
    if (e < NE) atomicAdd(&counts[clampi(recv[e], 0, NN - 1)], 1);
}

__global__ void scan_counts(const int* __restrict__ counts, int* __restrict__ rowstart) {
    __shared__ int part[1024];
    int t = threadIdx.x;
    const int CH = 10;
    int base = t * CH;
    int loc[CH];
    int s = 0;
#pragma unroll
    for (int j = 0; j < CH; j++) {
        int v = (base + j < NN) ? counts[base + j] : 0;
        loc[j] = s; s += v;
    }
    part[t] = s;
    __syncthreads();
    for (int off = 1; off < 1024; off <<= 1) {
        int v = (t >= off) ? part[t - off] : 0;
        __syncthreads();
        part[t] += v;
        __syncthreads();
    }
    int chunk = (t > 0) ? part[t - 1] : 0;
#pragma unroll
    for (int j = 0; j < CH; j++)
        if (base + j < NN) rowstart[base + j] = chunk + loc[j];
    if (t == 0) rowstart[NN] = part[1023];
}

__global__ void scatter_edges(const int* __restrict__ recv, const int* __restrict__ send,
                              const int* __restrict__ rowstart,
                              int* __restrict__ cursor, int* __restrict__ elist,
                              int* __restrict__ send2) {
    int e = blockIdx.x * blockDim.x + threadIdx.x;
    if (e < NE) {
        int r = clampi(recv[e], 0, NN - 1);
        int p = atomicAdd(&cursor[r], 1);
        int slot = clampi(rowstart[r] + p, 0, NE - 1);
        elist[slot] = e;
        send2[slot] = clampi(send[e], 0, NN - 1);
    }
}

// ---------------- edge MLP (r17 structure): 64 edges/block, 4 waves; 16KB LDS; fp8 output ----------------
__global__ __launch_bounds__(256) void edge_mlp(const float* __restrict__ ef2,
                                                const float* __restrict__ w1,
                                                const f16* __restrict__ w2T, const f16* __restrict__ w3T,
                                                const f16* __restrict__ w4T,
                                                unsigned char* __restrict__ Rw8) {
    __shared__ __align__(16) char L[16384];
    char* X1 = L;           // [64][64] f16 swz ^((row&7)<<4)
    char* X2 = L + 8192;    // stage2 out; reused as stage-4 slab

    int tid = threadIdx.x;
    int lane = tid & 63;
    int w = tid >> 6;
    int ln = lane & 15, kq = lane >> 4;
    int eb = blockIdx.x * 64;

    // ---- stage 1 (8 -> 64) scalar f32, thread = slot, wave = 16-col slice ----
    {
        int jb = w * 16;
        const float4* efv = (const float4*)(ef2 + (size_t)(eb + lane) * 8);
        float4 ea = efv[0], eb4 = efv[1];
        float in8[8] = {ea.x, ea.y, ea.z, ea.w, eb4.x, eb4.y, eb4.z, eb4.w};
        f16 pk[16];
#pragma unroll
        for (int j = 0; j < 16; j++) {
            float a = 0.f;
#pragma unroll
            for (int b = 0; b < 8; b++) a += in8[b] * w1[b * 64 + jb + j];
            pk[j] = (f16)silu_f(a);
        }
        int base = lane * 128 + jb * 2;
#pragma unroll
        for (int t = 0; t < 2; t++) {
            int byte = (base + t * 16) ^ ((lane & 7) << 4);
            *(uint4*)(X1 + byte) = ((uint4*)pk)[t];
        }
    }
    __syncthreads();

    // ---- stage 2 (64->64) MFMA: X1 -> X2 ----
    {
        half8 a[2];
#pragma unroll
        for (int kc = 0; kc < 2; kc++) {
            int row = w * 16 + ln;
            int byte = (row * 128 + kc * 64 + kq * 16) ^ ((row & 7) << 4);
            a[kc] = *(const half8*)(X1 + byte);
        }
#pragma unroll
        for (int nt = 0; nt < 4; nt++) {
            f32x4 acc = {0.f, 0.f, 0.f, 0.f};
#pragma unroll
            for (int kc = 0; kc < 2; kc++) {
                half8 b = *(const half8*)(w2T + (nt * 16 + ln) * 64 + kc * 32 + kq * 8);
                acc = __builtin_amdgcn_mfma_f32_16x16x32_f16(a[kc], b, acc, 0, 0, 0);
            }
#pragma unroll
            for (int r = 0; r < 4; r++) {
                int row = w * 16 + kq * 4 + r;
                int byte = (row * 128 + (nt * 16 + ln) * 2) ^ ((row & 7) << 4);
                *(f16*)(X2 + byte) = (f16)silu_f(acc[r]);
            }
        }
    }
    __syncthreads();

    // ---- stage 3 (64->64) MFMA: X2 -> X1 ----
    {
        half8 a[2];
#pragma unroll
        for (int kc = 0; kc < 2; kc++) {
            int row = w * 16 + ln;
            int byte = (row * 128 + kc * 64 + kq * 16) ^ ((row & 7) << 4);
            a[kc] = *(const half8*)(X2 + byte);
        }
#pragma unroll
        for (int nt = 0; nt < 4; nt++) {
            f32x4 acc = {0.f, 0.f, 0.f, 0.f};
#pragma unroll
            for (int kc = 0; kc < 2; kc++) {
                half8 b = *(const half8*)(w3T + (nt * 16 + ln) * 64 + kc * 32 + kq * 8);
                acc = __builtin_amdgcn_mfma_f32_16x16x32_f16(a[kc], b, acc, 0, 0, 0);
            }
#pragma unroll
            for (int r = 0; r < 4; r++) {
                int row = w * 16 + kq * 4 + r;
                int byte = (row * 128 + (nt * 16 + ln) * 2) ^ ((row & 7) << 4);
                *(f16*)(X1 + byte) = (f16)silu_f(acc[r]);
            }
        }
    }
    __syncthreads();   // X1=F3 ready; X2 free for stage-4 slabs

    // ---- stage 4 (64 -> 512): 8 slabs of 64 cols; f16 slab in X2 -> fp8 global ----
    half8 a3[2];
#pragma unroll
    for (int kc = 0; kc < 2; kc++) {
        int row = w * 16 + ln;
        int byte = (row * 128 + kc * 64 + kq * 16) ^ ((row & 7) << 4);
        a3[kc] = *(const half8*)(X1 + byte);
    }
    for (int s = 0; s < 8; s++) {
#pragma unroll
        for (int nt = 0; nt < 4; nt++) {
            f32x4 acc = {0.f, 0.f, 0.f, 0.f};
#pragma unroll
            for (int kc = 0; kc < 2; kc++) {
                half8 b = *(const half8*)(w4T + (s * 64 + nt * 16 + ln) * 64 + kc * 32 + kq * 8);
                acc = __builtin_amdgcn_mfma_f32_16x16x32_f16(a3[kc], b, acc, 0, 0, 0);
            }
#pragma unroll
            for (int r = 0; r < 4; r++) {
                int row = w * 16 + kq * 4 + r;
                int byte = (row * 128 + (nt * 16 + ln) * 2) ^ ((row & 7) << 4);
                *(f16*)(X2 + byte) = (f16)acc[r];
            }
        }
        __syncthreads();   // slab ready
#pragma unroll
        for (int it = 0; it < 2; it++) {
            int i = it * 256 + tid;          // 512 items: 16B f16 -> 8B fp8
            int row = i >> 3, chunk = i & 7;
            int byte = (row * 128 + chunk * 16) ^ ((row & 7) << 4);
            uint4 v = *(const uint4*)(X2 + byte);
            *(uint2*)(Rw8 + (size_t)(eb + row) * 512 + s * 64 + chunk * 8) = cvt8_fp8(v);
        }
        __syncthreads();   // X2 free for next slab
    }
}

// ---------------- aggregation (STREAMING, fp8 Rw) ----------------
__global__ __launch_bounds__(256) void agg_only(const int* __restrict__ rowstart,
                                                const int* __restrict__ send2, const float* __restrict__ h_in,
                                                const unsigned char* __restrict__ Rw8, const float* __restrict__ Y2,
                                                f16* __restrict__ aggH) {
    __shared__ int sL[64];
    int n = blockIdx.x, tid = threadIdx.x;
    int c = tid & 127, mh = tid >> 7;
    float acc[8];
#pragma unroll
    for (int q = 0; q < 8; q++) acc[q] = 0.f;
    int beg = rowstart[n], end = rowstart[n + 1];
    for (int base = beg; base < end; base += 64) {
        int cnt = min(64, end - base);
        __syncthreads();
        if (tid < cnt) sL[tid] = send2[base + tid];
        __syncthreads();
        for (int j = 0; j < cnt; j++) {
            int idx = base + j;
            int s = sL[j];
            float hs = h_in[(size_t)s * NC + c];
            const unsigned char* rwp = Rw8 + (size_t)idx * 512;
            const float4* yv = (const float4*)(Y2 + (size_t)idx * 16 + mh * 8);
            float4 ya = yv[0], yb = yv[1];
            float y[8] = {ya.x, ya.y, ya.z, ya.w, yb.x, yb.y, yb.z, yb.w};
            if (mh == 0) {
                float p0 = fp8_to_f(rwp[c]) * hs;
                float p1 = fp8_to_f(rwp[128 + c]) * hs;
                float p2 = fp8_to_f(rwp[256 + c]) * hs;
                acc[0] += p0 * y[0];
                acc[1] += p1 * y[1]; acc[2] += p1 * y[2]; acc[3] += p1 * y[3];
                acc[4] += p2 * y[4]; acc[5] += p2 * y[5]; acc[6] += p2 * y[6]; acc[7] += p2 * y[7];
            } else {
                float p2 = fp8_to_f(rwp[256 + c]) * hs;
                float p3 = fp8_to_f(rwp[384 + c]) * hs;
                acc[0] += p2 * y[0];
#pragma unroll
                for (int q = 1; q < 8; q++) acc[q] += p3 * y[q];
            }
        }
    }
    const float inv16 = 1.0f / 16.0f;
#pragma unroll
    for (int q = 0; q < 8; q++)
        aggH[(size_t)n * 2048 + (size_t)(mh * 8 + q) * NC + c] = (f16)(acc[q] * inv16);
}

// ---------------- mix_a: Wmix + invariants; block = (16 nodes, 64 d-cols); 4 waves; no barriers ----
__global__ __launch_bounds__(256) void mix_a(
    const f16* __restrict__ aggH, const f16* __restrict__ WmixT,
    const float* __restrict__ wU, f16* __restrict__ invwG, int layer)
{
    __shared__ __align__(16) char Lb[16384];   // 4 x 4KB wave-private B slices

    int tid = threadIdx.x;
    int b = blockIdx.x;
    int nb = (b >> 1) * 16;
    int half = b & 1;
    int lane = tid & 63;
    int w = tid >> 6;               // 0..3
    int dt = half * 4 + w;          // d-tile 0..7
    int ln = lane & 15, kq = lane >> 4;
    char* myB = Lb + w * 4096;

    float4 wUreg[4];
#pragma unroll
    for (int r = 0; r < 4; r++)
        wUreg[r] = *(const float4*)(wU + (size_t)(nb + kq * 4 + r) * 4);

    float invwacc[4] = {0.f, 0.f, 0.f, 0.f};
    const f16* aggRow = aggH + (size_t)(nb + ln) * 2048 + kq * 8;

#pragma unroll
    for (int g = 0; g < 4; g++) {
        const int mstart = (g == 0) ? 0 : (g == 1) ? 1 : (g == 2) ? 4 : 9;
        const int mend   = (g == 0) ? 1 : (g == 1) ? 4 : (g == 2) ? 9 : 16;
        {
            const f16* Bt = WmixT + ((size_t)(layer * 4 + g) << 14);
#pragma unroll
            for (int i = 0; i < 4; i++) {
                int q = i * 64 + lane;           // 0..255
                int row = q >> 4, col = q & 15;
                uint4 v = *(const uint4*)(Bt + (dt * 16 + row) * 128 + col * 8);
                int byte = (row * 256 + col * 16) ^ ((row & 7) << 4);
                *(uint4*)(myB + byte) = v;
            }
        }
#pragma unroll
        for (int m = mstart; m < mend; m++) {
            f32x4 acc = {0.f, 0.f, 0.f, 0.f};
#pragma unroll
            for (int k = 0; k < 4; k++) {
                half8 a = *(const half8*)(aggRow + m * 128 + k * 32);
                int byte = (ln * 256 + k * 64 + kq * 16) ^ ((ln & 7) << 4);
                half8 bb = *(const half8*)(myB + byte);
                acc = __builtin_amdgcn_mfma_f32_16x16x32_f16(a, bb, acc, 0, 0, 0);
            }
#pragma unroll
            for (int r = 0; r < 4; r++) {
                float wur = (g == 0) ? wUreg[r].x : (g == 1) ? wUreg[r].y : (g == 2) ? wUreg[r].z : wUreg[r].w;
                invwacc[r] += acc[r] * acc[r] * wur;
            }
        }
    }

#pragma unroll
    for (int r = 0; r < 4; r++)
        invwG[(size_t)(nb + kq * 4 + r) * 128 + dt * 16 + ln] = (f16)invwacc[r];
}

// ---------------- mix_b: update + readout; 16 nodes/block, 8 waves ----------------
__global__ __launch_bounds__(512) void mix_b(
    const f16* __restrict__ invwG, const float* __restrict__ h_in,
    const f16* __restrict__ WprodT, const f16* __restrict__ WscT,
    const float* __restrict__ Wro0, const float* __restrict__ Wro1a, const float* __restrict__ Wro1b,
    float* __restrict__ h_out, float* __restrict__ ni, int layer)
{
    __shared__ __align__(16) char Lb[13312];
    f16*   invwH = (f16*)(Lb);              // [16][128] f16 swizzled (4KB)
    f16*   hH    = (f16*)(Lb + 4096);       // [16][128] f16 swizzled (4KB)
    f16*   houtH = (f16*)(Lb + 8192);       // [16][128] f16 linear (4KB)
    float* p16L  = (float*)(Lb + 12288);    // [16][16] (1KB)

    int tid = threadIdx.x;
    int nb = blockIdx.x * 16;
    int lane = tid & 63;
    int w = tid >> 6;
    int ln = lane & 15, kq = lane >> 4;

    if (tid < 256) {
        int node = tid >> 4, ch = tid & 15;
        int byte = (node * 256 + ch * 16) ^ ((node & 7) << 4);
        uint4 iv = *(const uint4*)(invwG + (size_t)(nb + node) * 128 + ch * 8);
        *(uint4*)((char*)invwH + byte) = iv;
        const float4* hp = (const float4*)(h_in + (size_t)(nb + node) * 128 + ch * 8);
        float4 g0 = hp[0], g1 = hp[1];
        *(uint4*)((char*)hH + byte) = pack8f(g0, g1);
    }
    __syncthreads();

    {
        half8 ai[4], ah[4];
#pragma unroll
        for (int k = 0; k < 4; k++) {
            int byte = (ln * 256 + (k * 32 + kq * 8) * 2) ^ ((ln & 7) << 4);
            ai[k] = *(const half8*)((char*)invwH + byte);
            ah[k] = *(const half8*)((char*)hH + byte);
        }
        const f16* Bp = WprodT + ((size_t)layer << 14);
        const f16* Bs = WscT + ((size_t)layer << 14);
        f32x4 acc = {0.f, 0.f, 0.f, 0.f};
#pragma unroll
        for (int k = 0; k < 4; k++) {
            half8 bb = *(const half8*)(Bp + (w * 16 + ln) * 128 + k * 32 + kq * 8);
            acc = __builtin_amdgcn_mfma_f32_16x16x32_f16(ai[k], bb, acc, 0, 0, 0);
        }
#pragma unroll
        for (int k = 0; k < 4; k++) {
            half8 bb = *(const half8*)(Bs + (w * 16 + ln) * 128 + k * 32 + kq * 8);
            acc = __builtin_amdgcn_mfma_f32_16x16x32_f16(ah[k], bb, acc, 0, 0, 0);
        }
#pragma unroll
        for (int r = 0; r < 4; r++) {
            int node = kq * 4 + r;
            int d = w * 16 + ln;
            h_out[(size_t)(nb + node) * 128 + d] = acc[r];
            houtH[node * 128 + d] = (f16)acc[r];
        }
    }
    __syncthreads();

    if (tid < 256) {
        int rn = tid >> 4, rj = tid & 15;
        if (layer == 0) {
            float s = 0.f;
            for (int cc = rj; cc < 128; cc += 16) s += (float)houtH[rn * 128 + cc] * Wro0[cc];
            p16L[tid] = s;
        } else {
            float s = 0.f;
            for (int cc = 0; cc < 128; cc++) s += (float)houtH[rn * 128 + cc] * Wro1a[cc * 16 + rj];
            s = silu_f(s);
            p16L[tid] = s * Wro1b[rj];
        }
    }
    __syncthreads();
    if (tid < 16) {
        float t = 0.f;
#pragma unroll
        for (int j = 0; j < 16; j++) t += p16L[tid * 16 + j];
        ni[nb + tid] = (layer == 0) ? t : (ni[nb + tid] + t);
    }
}

// ---------------- finalize: per-graph totals ----------------
__global__ void finalize(const float* __restrict__ node_e0, const float* __restrict__ ni,
                         const int* __restrict__ batch, const float* __restrict__ scale,
                         const float* __restrict__ shift, float* __restrict__ out) {
    __shared__ float bins[NG];
    int tid = threadIdx.x;
    if (tid < NG) bins[tid] = 0.f;
    __syncthreads();
    int n = blockIdx.x * blockDim.x + tid;
    if (n < NN) {
        float v = node_e0[n] + scale[0] * ni[n] + shift[0];
        atomicAdd(&bins[clampi(batch[n], 0, NG - 1)], v);
    }
    __syncthreads();
    if (tid < NG) atomicAdd(&out[tid], bins[tid]);
}

extern "C" void kernel_launch(void* const* d_in, const int* in_sizes, int n_in,
                              void* d_out, int out_size, void* d_ws, size_t ws_size,
                              hipStream_t stream) {
    (void)in_sizes; (void)n_in; (void)out_size; (void)ws_size;
    const float* vectors = (const float*)d_in[0];
    const float* attrs   = (const float*)d_in[1];
    const float* W_embed = (const float*)d_in[2];
    const float* ae      = (const float*)d_in[3];
    const float* rw1     = (const float*)d_in[4];
    const float* rw2     = (const float*)d_in[5];
    const float* rw3     = (const float*)d_in[6];
    const float* rw4     = (const float*)d_in[7];
    const float* Wmix    = (const float*)d_in[8];
    const float* U       = (const float*)d_in[9];
    const float* Wprod   = (const float*)d_in[10];
    const float* Wsc     = (const float*)d_in[11];
    const float* Wro0    = (const float*)d_in[12];
    const float* Wro1a   = (const float*)d_in[13];
    const float* Wro1b   = (const float*)d_in[14];
    const float* scale   = (const float*)d_in[15];
    const float* shift   = (const float*)d_in[16];
    const int* eidx      = (const int*)d_in[17];
    const int* batch     = (const int*)d_in[18];
    float* out = (float*)d_out;

    char* w = (char*)d_ws;
    size_t off = 0;
    auto alloc = [&](size_t bytes) -> void* {
        void* p = (void*)(w + off);
        off += (bytes + 255) & ~(size_t)255;
        return p;
    };
    float* Y2      = (float*)alloc((size_t)NE * 16 * 4);       // 5.12 MB (slot order)
    float* ef2     = (float*)alloc((size_t)NE * 8 * 4);        // 2.56 MB (slot order)
    unsigned char* Rw8 = (unsigned char*)alloc((size_t)NE * 512); // 40.96 MB fp8 (slot order)
    f16*   aggH    = (f16*)  alloc((size_t)NN * 2048 * 2);     // 40.96 MB
    float* hA      = (float*)alloc((size_t)NN * NC * 4);
    float* hB      = (float*)alloc((size_t)NN * NC * 4);
    f16*   invwG   = (f16*)  alloc((size_t)NN * NC * 2);       // 2.56 MB
    float* wU      = (float*)alloc((size_t)2 * NN * 4 * 4);
    float* node_e0 = (float*)alloc((size_t)NN * 4);
    float* ni      = (float*)alloc((size_t)NN * 4);
    f16*   WmixT   = (f16*)  alloc((size_t)2 * 4 * 128 * 128 * 2);
    f16*   WprodT  = (f16*)  alloc((size_t)2 * 128 * 128 * 2);
    f16*   WscT    = (f16*)  alloc((size_t)2 * 128 * 128 * 2);
    f16*   w2T     = (f16*)  alloc((size_t)2 * 64 * 64 * 2);
    f16*   w3T     = (f16*)  alloc((size_t)2 * 64 * 64 * 2);
    f16*   w4T     = (f16*)  alloc((size_t)2 * 512 * 64 * 2);
    int* counts    = (int*)alloc((size_t)NN * 4);
    int* rowstart  = (int*)alloc((size_t)(NN + 1) * 4);
    int* cursor    = (int*)alloc((size_t)NN * 4);
    int* elist     = (int*)alloc((size_t)NE * 4);
    int* send2     = (int*)alloc((size_t)NE * 4);
    // total ~105 MB

    const int* send = eidx;            // edge_index[0]
    const int* recv = eidx + NE;       // edge_index[1]
    zero_stuff<<<(NN + 255) / 256, 256, 0, stream>>>(counts, cursor, out);
    prep_weights<<<512, 256, 0, stream>>>(Wmix, Wprod, Wsc, rw2, rw3, rw4,
                                          WmixT, WprodT, WscT, w2T, w3T, w4T);
    node_init<<<(NN * NC + 255) / 256, 256, 0, stream>>>(attrs, W_embed, ae, U, hA, node_e0, wU);
    hist_recv<<<(NE + 255) / 256, 256, 0, stream>>>(recv, counts);
    scan_counts<<<1, 1024, 0, stream>>>(counts, rowstart);
    scatter_edges<<<(NE + 255) / 256, 256, 0, stream>>>(recv, send, rowstart, cursor, elist, send2);
    edge_geom<<<(NE + 255) / 256, 256, 0, stream>>>(vectors, elist, Y2, ef2);

    float* hcur = hA;
    float* hnext = hB;
    for (int layer = 0; layer < 2; layer++) {
        edge_mlp<<<NE / 64, 256, 0, stream>>>(
            ef2, rw1 + layer * 8 * 64,
            w2T + (size_t)layer * 64 * 64, w3T + (size_t)layer * 64 * 64,
            w4T + (size_t)layer * 512 * 64, Rw8);
        agg_only<<<NN, 256, 0, stream>>>(rowstart, send2, hcur, Rw8, Y2, aggH);
        mix_a<<<(NN / 16) * 2, 256, 0, stream>>>(
            aggH, WmixT, wU + (size_t)layer * NN * 4, invwG, layer);
        mix_b<<<NN / 16, 512, 0, stream>>>(
            invwG, hcur, WprodT, WscT, Wro0, Wro1a, Wro1b, hnext, ni, layer);
        float* t = hcur; hcur = hnext; hnext = t;
    }
    finalize<<<(NN + 255) / 256, 256, 0, stream>>>(node_e0, ni, batch, scale, shift, out);
}

// Round 21
// 332.864 us; speedup vs baseline: 1.0675x; 1.0675x over previous
//
#include <hip/hip_runtime.h>
#include <hip/hip_fp8.h>

#define NN 10000      // nodes
#define NE 80000      // edges
#define NG 32         // graphs
#define NZ 10         // elements
#define NC 128        // channels
#define RMAXF 5.0f

typedef _Float16 f16;
typedef _Float16 half8 __attribute__((ext_vector_type(8)));
typedef float f32x4 __attribute__((ext_vector_type(4)));

#if defined(__has_builtin)
#if __has_builtin(__builtin_amdgcn_cvt_pk_fp8_f32) && __has_builtin(__builtin_amdgcn_cvt_f32_fp8)
#define HW_FP8 1
#endif
#endif

__device__ __forceinline__ float silu_f(float x) {
    return x / (1.0f + __expf(-x));
}

__device__ __forceinline__ int clampi(int v, int lo, int hi) {
    return v < lo ? lo : (v > hi ? hi : v);
}

__device__ __forceinline__ uint4 pack8f(float4 a, float4 b) {
    union { f16 h[8]; uint4 u; } P;
    P.h[0] = (f16)a.x; P.h[1] = (f16)a.y; P.h[2] = (f16)a.z; P.h[3] = (f16)a.w;
    P.h[4] = (f16)b.x; P.h[5] = (f16)b.y; P.h[6] = (f16)b.z; P.h[7] = (f16)b.w;
    return P.u;
}

// 8 x f16 -> 8 x fp8 bytes (hardware cvt_pk when available)
__device__ __forceinline__ uint2 cvt8_fp8(uint4 v) {
    union { uint4 u; f16 h[8]; } I; I.u = v;
#ifdef HW_FP8
    int lo = 0, hi = 0;
    lo = __builtin_amdgcn_cvt_pk_fp8_f32((float)I.h[0], (float)I.h[1], lo, false);
    lo = __builtin_amdgcn_cvt_pk_fp8_f32((float)I.h[2], (float)I.h[3], lo, true);
    hi = __builtin_amdgcn_cvt_pk_fp8_f32((float)I.h[4], (float)I.h[5], hi, false);
    hi = __builtin_amdgcn_cvt_pk_fp8_f32((float)I.h[6], (float)I.h[7], hi, true);
    uint2 r; r.x = (unsigned)lo; r.y = (unsigned)hi; return r;
#else
    union { unsigned char b[8]; uint2 u2; } O;
#pragma unroll
    for (int j = 0; j < 8; j++) {
        __hip_fp8_e4m3 t((float)I.h[j]);
        O.b[j] = t.__x;
    }
    return O.u2;
#endif
}

__device__ __forceinline__ float fp8_to_f(unsigned char b) {
#ifdef HW_FP8
    return __builtin_amdgcn_cvt_f32_fp8((int)b, 0);
#else
    __hip_fp8_e4m3 t; t.__x = b;
    return (float)t;
#endif
}

// ---------------- zero scratch / output ----------------
__global__ void zero_stuff(int* counts, int* cursor, float* out) {
    int i = blockIdx.x * blockDim.x + threadIdx.x;
    if (i < NN) { counts[i] = 0; cursor[i] = 0; }
    if (i < NG) out[i] = 0.0f;
}

// ---------------- weight prep: f16 transposed tables ----------------
__global__ void prep_weights(const float* __restrict__ Wmix, const float* __restrict__ Wprod,
                             const float* __restrict__ Wsc,
                             const float* __restrict__ rw2, const float* __restrict__ rw3,
                             const float* __restrict__ rw4,
                             f16* __restrict__ WmixT, f16* __restrict__ WprodT, f16* __restrict__ WscT,
                             f16* __restrict__ w2T, f16* __restrict__ w3T, f16* __restrict__ w4T) {
    int i = blockIdx.x * blockDim.x + threadIdx.x;
    if (i < 2 * 4 * 128 * 128) {           // WmixT[g][d][cc] = Wmix[g][cc][d]
        int cc = i & 127, d = (i >> 7) & 127, g = i >> 14;
        WmixT[i] = (f16)Wmix[((size_t)g * 128 + cc) * 128 + d];
    }
    if (i < 2 * 128 * 128) {               // WprodT[ly][d][dd] = Wprod[ly][dd][d]
        int cc = i & 127, d = (i >> 7) & 127, g = i >> 14;
        WprodT[i] = (f16)Wprod[((size_t)g * 128 + cc) * 128 + d];
        WscT[i]   = (f16)Wsc[((size_t)g * 128 + cc) * 128 + d];
    }
    if (i < 2 * 512 * 64) {                // w4T[ly][j][k] = rw4[ly][k][j]
        int k = i & 63, j = (i >> 6) & 511, ly = i >> 15;
        w4T[i] = (f16)rw4[((size_t)ly * 64 + k) * 512 + j];
    }
    if (i < 2 * 64 * 64) {                 // w2T/w3T[ly][j][k] = rw[ly][k][j]
        int k = i & 63, j = (i >> 6) & 63, ly = i >> 12;
        w2T[i] = (f16)rw2[((size_t)ly * 64 + k) * 64 + j];
        w3T[i] = (f16)rw3[((size_t)ly * 64 + k) * 64 + j];
    }
}

// ---------------- node init: h0, node_e0, wU ----------------
__global__ void node_init(const float* __restrict__ attrs, const float* __restrict__ W_embed,
                          const float* __restrict__ ae, const float* __restrict__ U,
                          float* __restrict__ h, float* __restrict__ node_e0, float* __restrict__ wU) {
    int gid = blockIdx.x * blockDim.x + threadIdx.x;
    if (gid >= NN * NC) return;
    int n = gid >> 7, c = gid & 127;
    float a[NZ];
#pragma unroll
    for (int z = 0; z < NZ; z++) a[z] = attrs[n * NZ + z];
    float acc = 0.f;
#pragma unroll
    for (int z = 0; z < NZ; z++) acc += a[z] * W_embed[z * NC + c];
    h[(size_t)n * NC + c] = acc;
    if (c == 0) {
        float e = 0.f;
#pragma unroll
        for (int z = 0; z < NZ; z++) e += a[z] * ae[z];
        node_e0[n] = e;
    }
    if (c < 8) {
        int i = c >> 2, l = c & 3;
        float s = 0.f;
#pragma unroll
        for (int z = 0; z < NZ; z++) s += a[z] * U[i * NZ * 4 + z * 4 + l];
        wU[(size_t)i * NN * 4 + n * 4 + l] = s;
    }
}

// ---------------- edge geometry (PERMUTED): slot i <- edge elist[i] ----------------
__global__ void edge_geom(const float* __restrict__ vec, const int* __restrict__ elist,
                          float* __restrict__ Y2, float* __restrict__ ef2) {
    int i = blockIdx.x * blockDim.x + threadIdx.x;
    if (i >= NE) return;
    int e = clampi(elist[i], 0, NE - 1);
    float vx = vec[e * 3 + 0], vy = vec[e * 3 + 1], vz = vec[e * 3 + 2];
    float r = sqrtf(vx * vx + vy * vy + vz * vz);
    float inv = 1.0f / r;
    float x = vx * inv, y = vy * inv, z = vz * inv;
    const float s3 = 1.7320508075688772f;
    const float s5 = 2.23606797749979f;
    const float s15 = 3.872983346207417f;
    const float c9 = 2.091650066335189f;
    const float c10 = 10.246950765959598f;
    const float c11 = 1.6201851746019651f;
    const float c12 = 1.3228756555322954f;
    const float c14 = 5.123475382979799f;
    float o[16];
    o[0] = 1.0f;
    o[1] = s3 * x; o[2] = s3 * y; o[3] = s3 * z;
    o[4] = s15 * x * y; o[5] = s15 * y * z; o[6] = 0.5f * s5 * (3.f * z * z - 1.f);
    o[7] = s15 * x * z; o[8] = 0.5f * s15 * (x * x - y * y);
    o[9] = c9 * (3.f * x * x * y - y * y * y);
    o[10] = c10 * x * y * z;
    o[11] = c11 * y * (5.f * z * z - 1.f);
    o[12] = c12 * (5.f * z * z * z - 3.f * z);
    o[13] = c11 * x * (5.f * z * z - 1.f);
    o[14] = c14 * z * (x * x - y * y);
    o[15] = c9 * (x * x * x - 3.f * x * y * y);
#pragma unroll
    for (int m = 0; m < 16; m++) Y2[(size_t)i * 16 + m] = o[m];
    float xc = r / RMAXF;
    float cut = 0.0f;
    if (xc < 1.0f) {
        float x5 = xc * xc * xc * xc * xc;
        cut = 1.0f - 21.0f * x5 + 35.0f * x5 * xc - 15.0f * x5 * xc * xc;
    }
    float pref = sqrtf(2.0f / RMAXF) * inv * cut;
#pragma unroll
    for (int b = 0; b < 8; b++) {
        float arg = (float)(b + 1) * 3.14159265358979323846f * r / RMAXF;
        ef2[(size_t)i * 8 + b] = pref * sinf(arg);
    }
}

// ---------------- CSR build ----------------
__global__ void hist_recv(const int* __restrict__ recv, int* __restrict__ counts) {
    int e = blockIdx.x * blockDim.x + threadIdx.x;
    if (e < NE) atomicAdd(&counts[clampi(recv[e], 0, NN - 1)], 1);
}

__global__ void scan_counts(const int* __restrict__ counts, int* __restrict__ rowstart) {
    __shared__ int part[1024];
    int t = threadIdx.x;
    const int CH = 10;
    int base = t * CH;
    int loc[CH];
    int s = 0;
#pragma unroll
    for (int j = 0; j < CH; j++) {
        int v = (base + j < NN) ? counts[base + j] : 0;
        loc[j] = s; s += v;
    }
    part[t] = s;
    __syncthreads();
    for (int off = 1; off < 1024; off <<= 1) {
        int v = (t >= off) ? part[t - off] : 0;
        __syncthreads();
        part[t] += v;
        __syncthreads();
    }
    int chunk = (t > 0) ? part[t - 1] : 0;
#pragma unroll
    for (int j = 0; j < CH; j++)
        if (base + j < NN) rowstart[base + j] = chunk + loc[j];
    if (t == 0) rowstart[NN] = part[1023];
}

__global__ void scatter_edges(const int* __restrict__ recv, const int* __restrict__ send,
                              const int* __restrict__ rowstart,
                              int* __restrict__ cursor, int* __restrict__ elist,
                              int* __restrict__ send2) {
    int e = blockIdx.x * blockDim.x + threadIdx.x;
    if (e < NE) {
        int r = clampi(recv[e], 0, NN - 1);
        int p = atomicAdd(&cursor[r], 1);
        int slot = clampi(rowstart[r] + p, 0, NE - 1);
        elist[slot] = e;
        send2[slot] = clampi(send[e], 0, NN - 1);
    }
}

// ---------------- edge MLP (r17 structure): 64 edges/block, 4 waves; 16KB LDS; fp8 output (HW cvt) ----------------
__global__ __launch_bounds__(256) void edge_mlp(const float* __restrict__ ef2,
                                                const float* __restrict__ w1,
                                                const f16* __restrict__ w2T, const f16* __restrict__ w3T,
                                                const f16* __restrict__ w4T,
                                                unsigned char* __restrict__ Rw8) {
    __shared__ __align__(16) char L[16384];
    char* X1 = L;           // [64][64] f16 swz ^((row&7)<<4)
    char* X2 = L + 8192;    // stage2 out; reused as stage-4 slab

    int tid = threadIdx.x;
    int lane = tid & 63;
    int w = tid >> 6;
    int ln = lane & 15, kq = lane >> 4;
    int eb = blockIdx.x * 64;

    // ---- stage 1 (8 -> 64) scalar f32, thread = slot, wave = 16-col slice ----
    {
        int jb = w * 16;
        const float4* efv = (const float4*)(ef2 + (size_t)(eb + lane) * 8);
        float4 ea = efv[0], eb4 = efv[1];
        float in8[8] = {ea.x, ea.y, ea.z, ea.w, eb4.x, eb4.y, eb4.z, eb4.w};
        f16 pk[16];
#pragma unroll
        for (int j = 0; j < 16; j++) {
            float a = 0.f;
#pragma unroll
            for (int b = 0; b < 8; b++) a += in8[b] * w1[b * 64 + jb + j];
            pk[j] = (f16)silu_f(a);
        }
        int base = lane * 128 + jb * 2;
#pragma unroll
        for (int t = 0; t < 2; t++) {
            int byte = (base + t * 16) ^ ((lane & 7) << 4);
            *(uint4*)(X1 + byte) = ((uint4*)pk)[t];
        }
    }
    __syncthreads();

    // ---- stage 2 (64->64) MFMA: X1 -> X2 ----
    {
        half8 a[2];
#pragma unroll
        for (int kc = 0; kc < 2; kc++) {
            int row = w * 16 + ln;
            int byte = (row * 128 + kc * 64 + kq * 16) ^ ((row & 7) << 4);
            a[kc] = *(const half8*)(X1 + byte);
        }
#pragma unroll
        for (int nt = 0; nt < 4; nt++) {
            f32x4 acc = {0.f, 0.f, 0.f, 0.f};
#pragma unroll
            for (int kc = 0; kc < 2; kc++) {
                half8 b = *(const half8*)(w2T + (nt * 16 + ln) * 64 + kc * 32 + kq * 8);
                acc = __builtin_amdgcn_mfma_f32_16x16x32_f16(a[kc], b, acc, 0, 0, 0);
            }
#pragma unroll
            for (int r = 0; r < 4; r++) {
                int row = w * 16 + kq * 4 + r;
                int byte = (row * 128 + (nt * 16 + ln) * 2) ^ ((row & 7) << 4);
                *(f16*)(X2 + byte) = (f16)silu_f(acc[r]);
            }
        }
    }
    __syncthreads();

    // ---- stage 3 (64->64) MFMA: X2 -> X1 ----
    {
        half8 a[2];
#pragma unroll
        for (int kc = 0; kc < 2; kc++) {
            int row = w * 16 + ln;
            int byte = (row * 128 + kc * 64 + kq * 16) ^ ((row & 7) << 4);
            a[kc] = *(const half8*)(X2 + byte);
        }
#pragma unroll
        for (int nt = 0; nt < 4; nt++) {
            f32x4 acc = {0.f, 0.f, 0.f, 0.f};
#pragma unroll
            for (int kc = 0; kc < 2; kc++) {
                half8 b = *(const half8*)(w3T + (nt * 16 + ln) * 64 + kc * 32 + kq * 8);
                acc = __builtin_amdgcn_mfma_f32_16x16x32_f16(a[kc], b, acc, 0, 0, 0);
            }
#pragma unroll
            for (int r = 0; r < 4; r++) {
                int row = w * 16 + kq * 4 + r;
                int byte = (row * 128 + (nt * 16 + ln) * 2) ^ ((row & 7) << 4);
                *(f16*)(X1 + byte) = (f16)silu_f(acc[r]);
            }
        }
    }
    __syncthreads();   // X1=F3 ready; X2 free for stage-4 slabs

    // ---- stage 4 (64 -> 512): 8 slabs of 64 cols; f16 slab in X2 -> fp8 global (HW cvt) ----
    half8 a3[2];
#pragma unroll
    for (int kc = 0; kc < 2; kc++) {
        int row = w * 16 + ln;
        int byte = (row * 128 + kc * 64 + kq * 16) ^ ((row & 7) << 4);
        a3[kc] = *(const half8*)(X1 + byte);
    }
    for (int s = 0; s < 8; s++) {
#pragma unroll
        for (int nt = 0; nt < 4; nt++) {
            f32x4 acc = {0.f, 0.f, 0.f, 0.f};
#pragma unroll
            for (int kc = 0; kc < 2; kc++) {
                half8 b = *(const half8*)(w4T + (s * 64 + nt * 16 + ln) * 64 + kc * 32 + kq * 8);
                acc = __builtin_amdgcn_mfma_f32_16x16x32_f16(a3[kc], b, acc, 0, 0, 0);
            }
#pragma unroll
            for (int r = 0; r < 4; r++) {
                int row = w * 16 + kq * 4 + r;
                int byte = (row * 128 + (nt * 16 + ln) * 2) ^ ((row & 7) << 4);
                *(f16*)(X2 + byte) = (f16)acc[r];
            }
        }
        __syncthreads();   // slab ready
#pragma unroll
        for (int it = 0; it < 2; it++) {
            int i = it * 256 + tid;          // 512 items: 16B f16 -> 8B fp8
            int row = i >> 3, chunk = i & 7;
            int byte = (row * 128 + chunk * 16) ^ ((row & 7) << 4);
            uint4 v = *(const uint4*)(X2 + byte);
            *(uint2*)(Rw8 + (size_t)(eb + row) * 512 + s * 64 + chunk * 8) = cvt8_fp8(v);
        }
        __syncthreads();   // X2 free for next slab
    }
}

// ---------------- aggregation (STREAMING, fp8 Rw, HW decode) ----------------
__global__ __launch_bounds__(256) void agg_only(const int* __restrict__ rowstart,
                                                const int* __restrict__ send2, const float* __restrict__ h_in,
                                                const unsigned char* __restrict__ Rw8, const float* __restrict__ Y2,
                                                f16* __restrict__ aggH) {
    __shared__ int sL[64];
    int n = blockIdx.x, tid = threadIdx.x;
    int c = tid & 127, mh = tid >> 7;
    float acc[8];
#pragma unroll
    for (int q = 0; q < 8; q++) acc[q] = 0.f;
    int beg = rowstart[n], end = rowstart[n + 1];
    for (int base = beg; base < end; base += 64) {
        int cnt = min(64, end - base);
        __syncthreads();
        if (tid < cnt) sL[tid] = send2[base + tid];
        __syncthreads();
        for (int j = 0; j < cnt; j++) {
            int idx = base + j;
            int s = sL[j];
            float hs = h_in[(size_t)s * NC + c];
            const unsigned char* rwp = Rw8 + (size_t)idx * 512;
            const float4* yv = (const float4*)(Y2 + (size_t)idx * 16 + mh * 8);
            float4 ya = yv[0], yb = yv[1];
            float y[8] = {ya.x, ya.y, ya.z, ya.w, yb.x, yb.y, yb.z, yb.w};
            if (mh == 0) {
                float p0 = fp8_to_f(rwp[c]) * hs;
                float p1 = fp8_to_f(rwp[128 + c]) * hs;
                float p2 = fp8_to_f(rwp[256 + c]) * hs;
                acc[0] += p0 * y[0];
                acc[1] += p1 * y[1]; acc[2] += p1 * y[2]; acc[3] += p1 * y[3];
                acc[4] += p2 * y[4]; acc[5] += p2 * y[5]; acc[6] += p2 * y[6]; acc[7] += p2 * y[7];
            } else {
                float p2 = fp8_to_f(rwp[256 + c]) * hs;
                float p3 = fp8_to_f(rwp[384 + c]) * hs;
                acc[0] += p2 * y[0];
#pragma unroll
                for (int q = 1; q < 8; q++) acc[q] += p3 * y[q];
            }
        }
    }
    const float inv16 = 1.0f / 16.0f;
#pragma unroll
    for (int q = 0; q < 8; q++)
        aggH[(size_t)n * 2048 + (size_t)(mh * 8 + q) * NC + c] = (f16)(acc[q] * inv16);
}

// ---------------- mix_a: Wmix + invariants; block = (16 nodes, 64 d-cols); 4 waves; no barriers ----
__global__ __launch_bounds__(256) void mix_a(
    const f16* __restrict__ aggH, const f16* __restrict__ WmixT,
    const float* __restrict__ wU, f16* __restrict__ invwG, int layer)
{
    __shared__ __align__(16) char Lb[16384];   // 4 x 4KB wave-private B slices

    int tid = threadIdx.x;
    int b = blockIdx.x;
    int nb = (b >> 1) * 16;
    int half = b & 1;
    int lane = tid & 63;
    int w = tid >> 6;               // 0..3
    int dt = half * 4 + w;          // d-tile 0..7
    int ln = lane & 15, kq = lane >> 4;
    char* myB = Lb + w * 4096;

    float4 wUreg[4];
#pragma unroll
    for (int r = 0; r < 4; r++)
        wUreg[r] = *(const float4*)(wU + (size_t)(nb + kq * 4 + r) * 4);

    float invwacc[4] = {0.f, 0.f, 0.f, 0.f};
    const f16* aggRow = aggH + (size_t)(nb + ln) * 2048 + kq * 8;

#pragma unroll
    for (int g = 0; g < 4; g++) {
        const int mstart = (g == 0) ? 0 : (g == 1) ? 1 : (g == 2) ? 4 : 9;
        const int mend   = (g == 0) ? 1 : (g == 1) ? 4 : (g == 2) ? 9 : 16;
        {
            const f16* Bt = WmixT + ((size_t)(layer * 4 + g) << 14);
#pragma unroll
            for (int i = 0; i < 4; i++) {
                int q = i * 64 + lane;           // 0..255
                int row = q >> 4, col = q & 15;
                uint4 v = *(const uint4*)(Bt + (dt * 16 + row) * 128 + col * 8);
                int byte = (row * 256 + col * 16) ^ ((row & 7) << 4);
                *(uint4*)(myB + byte) = v;
            }
        }
#pragma unroll
        for (int m = mstart; m < mend; m++) {
            f32x4 acc = {0.f, 0.f, 0.f, 0.f};
#pragma unroll
            for (int k = 0; k < 4; k++) {
                half8 a = *(const half8*)(aggRow + m * 128 + k * 32);
                int byte = (ln * 256 + k * 64 + kq * 16) ^ ((ln & 7) << 4);
                half8 bb = *(const half8*)(myB + byte);
                acc = __builtin_amdgcn_mfma_f32_16x16x32_f16(a, bb, acc, 0, 0, 0);
            }
#pragma unroll
            for (int r = 0; r < 4; r++) {
                float wur = (g == 0) ? wUreg[r].x : (g == 1) ? wUreg[r].y : (g == 2) ? wUreg[r].z : wUreg[r].w;
                invwacc[r] += acc[r] * acc[r] * wur;
            }
        }
    }

#pragma unroll
    for (int r = 0; r < 4; r++)
        invwG[(size_t)(nb + kq * 4 + r) * 128 + dt * 16 + ln] = (f16)invwacc[r];
}

// ---------------- mix_b: update + readout; 16 nodes/block, 8 waves ----------------
__global__ __launch_bounds__(512) void mix_b(
    const f16* __restrict__ invwG, const float* __restrict__ h_in,
    const f16* __restrict__ WprodT, const f16* __restrict__ WscT,
    const float* __restrict__ Wro0, const float* __restrict__ Wro1a, const float* __restrict__ Wro1b,
    float* __restrict__ h_out, float* __restrict__ ni, int layer)
{
    __shared__ __align__(16) char Lb[13312];
    f16*   invwH = (f16*)(Lb);              // [16][128] f16 swizzled (4KB)
    f16*   hH    = (f16*)(Lb + 4096);       // [16][128] f16 swizzled (4KB)
    f16*   houtH = (f16*)(Lb + 8192);       // [16][128] f16 linear (4KB)
    float* p16L  = (float*)(Lb + 12288);    // [16][16] (1KB)

    int tid = threadIdx.x;
    int nb = blockIdx.x * 16;
    int lane = tid & 63;
    int w = tid >> 6;
    int ln = lane & 15, kq = lane >> 4;

    if (tid < 256) {
        int node = tid >> 4, ch = tid & 15;
        int byte = (node * 256 + ch * 16) ^ ((node & 7) << 4);
        uint4 iv = *(const uint4*)(invwG + (size_t)(nb + node) * 128 + ch * 8);
        *(uint4*)((char*)invwH + byte) = iv;
        const float4* hp = (const float4*)(h_in + (size_t)(nb + node) * 128 + ch * 8);
        float4 g0 = hp[0], g1 = hp[1];
        *(uint4*)((char*)hH + byte) = pack8f(g0, g1);
    }
    __syncthreads();

    {
        half8 ai[4], ah[4];
#pragma unroll
        for (int k = 0; k < 4; k++) {
            int byte = (ln * 256 + (k * 32 + kq * 8) * 2) ^ ((ln & 7) << 4);
            ai[k] = *(const half8*)((char*)invwH + byte);
            ah[k] = *(const half8*)((char*)hH + byte);
        }
        const f16* Bp = WprodT + ((size_t)layer << 14);
        const f16* Bs = WscT + ((size_t)layer << 14);
        f32x4 acc = {0.f, 0.f, 0.f, 0.f};
#pragma unroll
        for (int k = 0; k < 4; k++) {
            half8 bb = *(const half8*)(Bp + (w * 16 + ln) * 128 + k * 32 + kq * 8);
            acc = __builtin_amdgcn_mfma_f32_16x16x32_f16(ai[k], bb, acc, 0, 0, 0);
        }
#pragma unroll
        for (int k = 0; k < 4; k++) {
            half8 bb = *(const half8*)(Bs + (w * 16 + ln) * 128 + k * 32 + kq * 8);
            acc = __builtin_amdgcn_mfma_f32_16x16x32_f16(ah[k], bb, acc, 0, 0, 0);
        }
#pragma unroll
        for (int r = 0; r < 4; r++) {
            int node = kq * 4 + r;
            int d = w * 16 + ln;
            h_out[(size_t)(nb + node) * 128 + d] = acc[r];
            houtH[node * 128 + d] = (f16)acc[r];
        }
    }
    __syncthreads();

    if (tid < 256) {
        int rn = tid >> 4, rj = tid & 15;
        if (layer == 0) {
            float s = 0.f;
            for (int cc = rj; cc < 128; cc += 16) s += (float)houtH[rn * 128 + cc] * Wro0[cc];
            p16L[tid] = s;
        } else {
            float s = 0.f;
            for (int cc = 0; cc < 128; cc++) s += (float)houtH[rn * 128 + cc] * Wro1a[cc * 16 + rj];
            s = silu_f(s);
            p16L[tid] = s * Wro1b[rj];
        }
    }
    __syncthreads();
    if (tid < 16) {
        float t = 0.f;
#pragma unroll
        for (int j = 0; j < 16; j++) t += p16L[tid * 16 + j];
        ni[nb + tid] = (layer == 0) ? t : (ni[nb + tid] + t);
    }
}

// ---------------- finalize: per-graph totals ----------------
__global__ void finalize(const float* __restrict__ node_e0, const float* __restrict__ ni,
                         const int* __restrict__ batch, const float* __restrict__ scale,
                         const float* __restrict__ shift, float* __restrict__ out) {
    __shared__ float bins[NG];
    int tid = threadIdx.x;
    if (tid < NG) bins[tid] = 0.f;
    __syncthreads();
    int n = blockIdx.x * blockDim.x + tid;
    if (n < NN) {
        float v = node_e0[n] + scale[0] * ni[n] + shift[0];
        atomicAdd(&bins[clampi(batch[n], 0, NG - 1)], v);
    }
    __syncthreads();
    if (tid < NG) atomicAdd(&out[tid], bins[tid]);
}

extern "C" void kernel_launch(void* const* d_in, const int* in_sizes, int n_in,
                              void* d_out, int out_size, void* d_ws, size_t ws_size,
                              hipStream_t stream) {
    (void)in_sizes; (void)n_in; (void)out_size; (void)ws_size;
    const float* vectors = (const float*)d_in[0];
    const float* attrs   = (const float*)d_in[1];
    const float* W_embed = (const float*)d_in[2];
    const float* ae      = (const float*)d_in[3];
    const float* rw1     = (const float*)d_in[4];
    const float* rw2     = (const float*)d_in[5];
    const float* rw3     = (const float*)d_in[6];
    const float* rw4     = (const float*)d_in[7];
    const float* Wmix    = (const float*)d_in[8];
    const float* U       = (const float*)d_in[9];
    const float* Wprod   = (const float*)d_in[10];
    const float* Wsc     = (const float*)d_in[11];
    const float* Wro0    = (const float*)d_in[12];
    const float* Wro1a   = (const float*)d_in[13];
    const float* Wro1b   = (const float*)d_in[14];
    const float* scale   = (const float*)d_in[15];
    const float* shift   = (const float*)d_in[16];
    const int* eidx      = (const int*)d_in[17];
    const int* batch     = (const int*)d_in[18];
    float* out = (float*)d_out;

    char* w = (char*)d_ws;
    size_t off = 0;
    auto alloc = [&](size_t bytes) -> void* {
        void* p = (void*)(w + off);
        off += (bytes + 255) & ~(size_t)255;
        return p;
    };
    float* Y2      = (float*)alloc((size_t)NE * 16 * 4);       // 5.12 MB (slot order)
    float* ef2     = (float*)alloc((size_t)NE * 8 * 4);        // 2.56 MB (slot order)
    unsigned char* Rw8 = (unsigned char*)alloc((size_t)NE * 512); // 40.96 MB fp8 (slot order)
    f16*   aggH    = (f16*)  alloc((size_t)NN * 2048 * 2);     // 40.96 MB
    float* hA      = (float*)alloc((size_t)NN * NC * 4);
    float* hB      = (float*)alloc((size_t)NN * NC * 4);
    f16*   invwG   = (f16*)  alloc((size_t)NN * NC * 2);       // 2.56 MB
    float* wU      = (float*)alloc((size_t)2 * NN * 4 * 4);
    float* node_e0 = (float*)alloc((size_t)NN * 4);
    float* ni      = (float*)alloc((size_t)NN * 4);
    f16*   WmixT   = (f16*)  alloc((size_t)2 * 4 * 128 * 128 * 2);
    f16*   WprodT  = (f16*)  alloc((size_t)2 * 128 * 128 * 2);
    f16*   WscT    = (f16*)  alloc((size_t)2 * 128 * 128 * 2);
    f16*   w2T     = (f16*)  alloc((size_t)2 * 64 * 64 * 2);
    f16*   w3T     = (f16*)  alloc((size_t)2 * 64 * 64 * 2);
    f16*   w4T     = (f16*)  alloc((size_t)2 * 512 * 64 * 2);
    int* counts    = (int*)alloc((size_t)NN * 4);
    int* rowstart  = (int*)alloc((size_t)(NN + 1) * 4);
    int* cursor    = (int*)alloc((size_t)NN * 4);
    int* elist     = (int*)alloc((size_t)NE * 4);
    int* send2     = (int*)alloc((size_t)NE * 4);
    // total ~105 MB

    const int* send = eidx;            // edge_index[0]
    const int* recv = eidx + NE;       // edge_index[1]
    zero_stuff<<<(NN + 255) / 256, 256, 0, stream>>>(counts, cursor, out);
    prep_weights<<<512, 256, 0, stream>>>(Wmix, Wprod, Wsc, rw2, rw3, rw4,
                                          WmixT, WprodT, WscT, w2T, w3T, w4T);
    node_init<<<(NN * NC + 255) / 256, 256, 0, stream>>>(attrs, W_embed, ae, U, hA, node_e0, wU);
    hist_recv<<<(NE + 255) / 256, 256, 0, stream>>>(recv, counts);
    scan_counts<<<1, 1024, 0, stream>>>(counts, rowstart);
    scatter_edges<<<(NE + 255) / 256, 256, 0, stream>>>(recv, send, rowstart, cursor, elist, send2);
    edge_geom<<<(NE + 255) / 256, 256, 0, stream>>>(vectors, elist, Y2, ef2);

    float* hcur = hA;
    float* hnext = hB;
    for (int layer = 0; layer < 2; layer++) {
        edge_mlp<<<NE / 64, 256, 0, stream>>>(
            ef2, rw1 + layer * 8 * 64,
            w2T + (size_t)layer * 64 * 64, w3T + (size_t)layer * 64 * 64,
            w4T + (size_t)layer * 512 * 64, Rw8);
        agg_only<<<NN, 256, 0, stream>>>(rowstart, send2, hcur, Rw8, Y2, aggH);
        mix_a<<<(NN / 16) * 2, 256, 0, stream>>>(
            aggH, WmixT, wU + (size_t)layer * NN * 4, invwG, layer);
        mix_b<<<NN / 16, 512, 0, stream>>>(
            invwG, hcur, WprodT, WscT, Wro0, Wro1a, Wro1b, hnext, ni, layer);
        float* t = hcur; hcur = hnext; hnext = t;
    }
    finalize<<<(NN + 255) / 256, 256, 0, stream>>>(node_e0, ni, batch, scale, shift, out);
}